// Round 2
// baseline (669.374 us; speedup 1.0000x reference)
//
#include <hip/hip_runtime.h>
#include <cstdint>
#include <cstddef>

#define NEGF (-1e30f)

typedef __attribute__((ext_vector_type(8))) short short8;
typedef __attribute__((ext_vector_type(4))) float f32x4;

// round-to-nearest-even fp32 -> bf16 bits
__device__ __forceinline__ unsigned short f2bf(float f) {
  unsigned int u = __float_as_uint(f);
  u += 0x7fffu + ((u >> 16) & 1u);
  return (unsigned short)(u >> 16);
}

__device__ __forceinline__ void gload_lds16(const void* g, void* l) {
  __builtin_amdgcn_global_load_lds(
      (const __attribute__((address_space(1))) void*)g,
      (__attribute__((address_space(3))) void*)l, 16, 0, 0);
}

__device__ __forceinline__ float lse3f(float a, float b, float c) {
  float m = fmaxf(fmaxf(a, b), c);
  return m + __logf(__expf(a - m) + __expf(b - m) + __expf(c - m));
}

// ---------------- convert kernels ----------------
__global__ void k_cvt(const float* __restrict__ src, unsigned short* __restrict__ dst, long n) {
  long i = ((long)blockIdx.x * blockDim.x + threadIdx.x) * 4;
  long stride = (long)gridDim.x * blockDim.x * 4;
  for (; i < n; i += stride) {
    float4 v = *(const float4*)(src + i);
    ushort4 o;
    o.x = f2bf(v.x); o.y = f2bf(v.y); o.z = f2bf(v.z); o.w = f2bf(v.w);
    *(ushort4*)(dst + i) = o;
  }
}

// W2 [101][512] fp32 -> padded [128][512] bf16 (rows >=101 zero)
__global__ void k_cvt_w2(const float* __restrict__ w2, unsigned short* __restrict__ dst) {
  int i = (blockIdx.x * blockDim.x + threadIdx.x) * 4;
  if (i >= 128 * 512) return;
  int c = i >> 9;
  float4 v = make_float4(0.f, 0.f, 0.f, 0.f);
  if (c < 101) v = *(const float4*)(w2 + i);
  ushort4 o;
  o.x = f2bf(v.x); o.y = f2bf(v.y); o.z = f2bf(v.z); o.w = f2bf(v.w);
  *(ushort4*)(dst + i) = o;
}

// ---------------- GEMM1: h = relu(X @ W1^T + b1), bf16 out ----------------
// X[64000][1024] bf16, W1[512][1024] bf16, H[64000][512] bf16
__global__ __launch_bounds__(256) void k_gemm1(
    const unsigned short* __restrict__ A,
    const unsigned short* __restrict__ B,
    const float* __restrict__ b1,
    unsigned short* __restrict__ H) {
  __shared__ __align__(16) char lds[32768];  // A tile [128][64] | B tile [128][64]
  const int K = 1024;
  int bid = blockIdx.x;
  // XCD-chunked swizzle, nwg=2000 (divisible by 8)
  int lid = (bid & 7) * 250 + (bid >> 3);
  int mt = lid >> 2, nt = lid & 3;
  int row0 = mt * 128, col0 = nt * 128;
  int tid = threadIdx.x;
  int lane = tid & 63, wid = tid >> 6;
  int wr = (wid >> 1) * 64, wc = (wid & 1) * 64;

  f32x4 acc[4][4];
#pragma unroll
  for (int i = 0; i < 4; ++i)
#pragma unroll
    for (int j = 0; j < 4; ++j) acc[i][j] = (f32x4){0.f, 0.f, 0.f, 0.f};

  for (int kt = 0; kt < 16; ++kt) {
    int k0 = kt * 64;
    __syncthreads();
#pragma unroll
    for (int r = 0; r < 4; ++r) {
      int c = r * 256 + tid;
      int trow = c >> 3;
      int sch = (c & 7) ^ (trow & 7);  // pre-swizzled global source chunk
      gload_lds16(A + (size_t)(row0 + trow) * K + (k0 + sch * 8), lds + c * 16);
      gload_lds16(B + (size_t)(col0 + trow) * K + (k0 + sch * 8), lds + 16384 + c * 16);
    }
    asm volatile("s_waitcnt vmcnt(0)" ::: "memory");
    __syncthreads();
#pragma unroll
    for (int kk = 0; kk < 2; ++kk) {
      int kb2 = (kk * 32 + ((lane >> 4) << 3)) * 2;  // byte offset along K
      short8 af[4], bfr[4];
#pragma unroll
      for (int i = 0; i < 4; ++i) {
        int ar = wr + i * 16 + (lane & 15);
        af[i] = *(const short8*)(lds + ((ar * 128 + kb2) ^ ((ar & 7) << 4)));
        int br = wc + i * 16 + (lane & 15);
        bfr[i] = *(const short8*)(lds + 16384 + ((br * 128 + kb2) ^ ((br & 7) << 4)));
      }
#pragma unroll
      for (int i = 0; i < 4; ++i)
#pragma unroll
        for (int j = 0; j < 4; ++j)
          acc[i][j] = __builtin_amdgcn_mfma_f32_16x16x32_bf16(af[i], bfr[j], acc[i][j], 0, 0, 0);
    }
  }
  int cl = lane & 15, r4 = (lane >> 4) << 2;
#pragma unroll
  for (int i = 0; i < 4; ++i) {
    int row = row0 + wr + i * 16 + r4;
#pragma unroll
    for (int j = 0; j < 4; ++j) {
      int col = col0 + wc + j * 16 + cl;
      float bb = b1[col];
#pragma unroll
      for (int q = 0; q < 4; ++q) {
        float v = acc[i][j][q] + bb;
        v = v > 0.f ? v : 0.f;
        H[(size_t)(row + q) * 512 + col] = f2bf(v);
      }
    }
  }
}

// ---------------- GEMM2 + log_softmax ----------------
// Hm[64000][512] bf16, W2[128][512] bf16 (padded), LP[64000][101] fp32
__global__ __launch_bounds__(256) void k_gemm2(
    const unsigned short* __restrict__ Hm,
    const unsigned short* __restrict__ W2,
    const float* __restrict__ b2,
    float* __restrict__ LP) {
  __shared__ __align__(16) char lds[32768];
  const int K = 512;
  int row0 = blockIdx.x * 128;
  int tid = threadIdx.x, lane = tid & 63, wid = tid >> 6;
  f32x4 acc[2][8];
#pragma unroll
  for (int i = 0; i < 2; ++i)
#pragma unroll
    for (int j = 0; j < 8; ++j) acc[i][j] = (f32x4){0.f, 0.f, 0.f, 0.f};

  for (int kt = 0; kt < 8; ++kt) {
    int k0 = kt * 64;
    __syncthreads();
#pragma unroll
    for (int r = 0; r < 4; ++r) {
      int c = r * 256 + tid;
      int trow = c >> 3;
      int sch = (c & 7) ^ (trow & 7);
      gload_lds16(Hm + (size_t)(row0 + trow) * K + (k0 + sch * 8), lds + c * 16);
      gload_lds16(W2 + (size_t)trow * K + (k0 + sch * 8), lds + 16384 + c * 16);
    }
    asm volatile("s_waitcnt vmcnt(0)" ::: "memory");
    __syncthreads();
#pragma unroll
    for (int kk = 0; kk < 2; ++kk) {
      int kb2 = (kk * 32 + ((lane >> 4) << 3)) * 2;
      short8 af[2], bfr[8];
#pragma unroll
      for (int i = 0; i < 2; ++i) {
        int ar = wid * 32 + i * 16 + (lane & 15);
        af[i] = *(const short8*)(lds + ((ar * 128 + kb2) ^ ((ar & 7) << 4)));
      }
#pragma unroll
      for (int j = 0; j < 8; ++j) {
        int br = j * 16 + (lane & 15);
        bfr[j] = *(const short8*)(lds + 16384 + ((br * 128 + kb2) ^ ((br & 7) << 4)));
      }
#pragma unroll
      for (int i = 0; i < 2; ++i)
#pragma unroll
        for (int j = 0; j < 8; ++j)
          acc[i][j] = __builtin_amdgcn_mfma_f32_16x16x32_bf16(af[i], bfr[j], acc[i][j], 0, 0, 0);
    }
  }
  // epilogue: bias + row log_softmax over cols 0..100, write fp32
  int cl = lane & 15, r4 = (lane >> 4) << 2;
#pragma unroll
  for (int i = 0; i < 2; ++i) {
#pragma unroll
    for (int q = 0; q < 4; ++q) {
      int row = row0 + wid * 32 + i * 16 + r4 + q;
      float v[8];
      float mx = NEGF;
#pragma unroll
      for (int j = 0; j < 8; ++j) {
        int col = j * 16 + cl;
        float t = acc[i][j][q];
        if (col < 101) {
          t += b2[col];
          mx = fmaxf(mx, t);
        }
        v[j] = t;
      }
#pragma unroll
      for (int m = 1; m < 16; m <<= 1) mx = fmaxf(mx, __shfl_xor(mx, m));
      float s = 0.f;
#pragma unroll
      for (int j = 0; j < 8; ++j) {
        int col = j * 16 + cl;
        if (col < 101) s += __expf(v[j] - mx);
      }
#pragma unroll
      for (int m = 1; m < 16; m <<= 1) s += __shfl_xor(s, m);
      float lse = mx + __logf(s);
#pragma unroll
      for (int j = 0; j < 8; ++j) {
        int col = j * 16 + cl;
        if (col < 101) LP[(size_t)row * 101 + col] = v[j] - lse;
      }
    }
  }
}

// ---------------- CTC alpha recursion: one wave per batch element ----------------
__global__ __launch_bounds__(64) void k_ctc(
    const float* __restrict__ LP,
    const int* __restrict__ tgt_all,
    const int* __restrict__ dlen,
    const int* __restrict__ tlen,
    float* __restrict__ lossout) {
  int b = blockIdx.x;
  int lane = threadIdx.x;
  const float* lp = LP + (size_t)b * 1000 * 101;
  int Tb = dlen[b];
  int Ub = tlen[b];
  const int* tg = tgt_all + b * 200;

  int cls[7], sk[7], val[7];
#pragma unroll
  for (int j = 0; j < 7; ++j) {
    int s = lane * 7 + j;
    int c = 100, skp = 0, vl = (s < 401) ? 1 : 0;
    if (vl && (s & 1)) {
      int u = (s - 1) >> 1;
      c = tg[u];
      if (s >= 3) skp = (tg[u] != tg[u - 1]) ? 1 : 0;
    }
    cls[j] = c; sk[j] = skp; val[j] = vl;
  }

  float al[7];
#pragma unroll
  for (int j = 0; j < 7; ++j) {
    int s = lane * 7 + j;
    al[j] = (s <= 1) ? lp[cls[j]] : NEGF;  // t=0 init
  }

  float pf[4][7];
#define LOADROW(tt, bi)                                      \
  do {                                                       \
    int ttc = (tt) < 1000 ? (tt) : 999;                      \
    const float* rp = lp + (size_t)ttc * 101;                \
    pf[bi][0] = rp[cls[0]]; pf[bi][1] = rp[cls[1]];          \
    pf[bi][2] = rp[cls[2]]; pf[bi][3] = rp[cls[3]];          \
    pf[bi][4] = rp[cls[4]]; pf[bi][5] = rp[cls[5]];          \
    pf[bi][6] = rp[cls[6]];                                  \
  } while (0)

  LOADROW(1, 0); LOADROW(2, 1); LOADROW(3, 2);

#define STEP(tt, cb, lb)                                                     \
  do {                                                                       \
    if ((tt) < Tb) {                                                         \
      LOADROW((tt) + 3, lb);                                                 \
      float u6 = __shfl_up(al[6], 1);                                        \
      float u5 = __shfl_up(al[5], 1);                                        \
      if (lane == 0) { u6 = NEGF; u5 = NEGF; }                               \
      float na0 = lse3f(al[0], u6, sk[0] ? u5 : NEGF) + pf[cb][0];           \
      float na1 = lse3f(al[1], al[0], sk[1] ? u6 : NEGF) + pf[cb][1];        \
      float na2 = lse3f(al[2], al[1], sk[2] ? al[0] : NEGF) + pf[cb][2];     \
      float na3 = lse3f(al[3], al[2], sk[3] ? al[1] : NEGF) + pf[cb][3];     \
      float na4 = lse3f(al[4], al[3], sk[4] ? al[2] : NEGF) + pf[cb][4];     \
      float na5 = lse3f(al[5], al[4], sk[5] ? al[3] : NEGF) + pf[cb][5];     \
      float na6 = lse3f(al[6], al[5], sk[6] ? al[4] : NEGF) + pf[cb][6];     \
      al[0] = val[0] ? na0 : NEGF;                                           \
      al[1] = val[1] ? na1 : NEGF;                                           \
      al[2] = val[2] ? na2 : NEGF;                                           \
      al[3] = val[3] ? na3 : NEGF;                                           \
      al[4] = val[4] ? na4 : NEGF;                                           \
      al[5] = val[5] ? na5 : NEGF;                                           \
      al[6] = val[6] ? na6 : NEGF;                                           \
    }                                                                        \
  } while (0)

  for (int t = 1; t < Tb; t += 4) {
    STEP(t, 0, 3);
    STEP(t + 1, 1, 0);
    STEP(t + 2, 2, 1);
    STEP(t + 3, 3, 2);
  }

  __shared__ float sal[401];
#pragma unroll
  for (int j = 0; j < 7; ++j) {
    int s = lane * 7 + j;
    if (s < 401) sal[s] = al[j];
  }
  __syncthreads();
  if (lane == 0) {
    float l1 = sal[2 * Ub];
    float l2 = sal[2 * Ub - 1];
    float m = fmaxf(l1, l2);
    float nll = -(m + __logf(__expf(l1 - m) + __expf(l2 - m)));
    lossout[b] = nll / (float)Tb;
  }
#undef STEP
#undef LOADROW
}

__global__ void k_reduce(const float* __restrict__ lossv, float* __restrict__ out) {
  float v = lossv[threadIdx.x];
#pragma unroll
  for (int m = 1; m < 64; m <<= 1) v += __shfl_xor(v, m);
  if (threadIdx.x == 0) out[0] = v * (1.0f / 64.0f);
}

extern "C" void kernel_launch(void* const* d_in, const int* in_sizes, int n_in,
                              void* d_out, int out_size, void* d_ws, size_t ws_size,
                              hipStream_t stream) {
  const float* X  = (const float*)d_in[0];
  const int* tgt  = (const int*)d_in[1];
  const int* dlen = (const int*)d_in[2];
  const int* tlen = (const int*)d_in[3];
  const float* W1 = (const float*)d_in[4];
  const float* b1 = (const float*)d_in[5];
  const float* W2 = (const float*)d_in[6];
  const float* b2 = (const float*)d_in[7];

  char* ws = (char*)d_ws;
  unsigned short* Xbf  = (unsigned short*)(ws);              // 131,072,000 B
  float* LP            = (float*)(ws);                       // overlaps Xbf (Xbf dead after gemm1)
  unsigned short* W1bf = (unsigned short*)(ws + 131072000);  // 1,048,576 B
  unsigned short* W2bf = (unsigned short*)(ws + 132120576);  // 131,072 B
  unsigned short* Hbf  = (unsigned short*)(ws + 132251648);  // 65,536,000 B
  float* lossv         = (float*)(ws + 197787648);           // 256 B

  k_cvt<<<4096, 256, 0, stream>>>(X, Xbf, 65536000L);
  k_cvt<<<512, 256, 0, stream>>>(W1, W1bf, 524288L);
  k_cvt_w2<<<64, 256, 0, stream>>>(W2, W2bf);
  k_gemm1<<<2000, 256, 0, stream>>>(Xbf, W1bf, b1, Hbf);
  k_gemm2<<<500, 256, 0, stream>>>(Hbf, W2bf, b2, LP);
  k_ctc<<<64, 64, 0, stream>>>(LP, tgt, dlen, tlen, lossv);
  k_reduce<<<1, 64, 0, stream>>>(lossv, (float*)d_out);
}

// Round 3
// 475.395 us; speedup vs baseline: 1.4080x; 1.4080x over previous
//
#include <hip/hip_runtime.h>
#include <cstdint>
#include <cstddef>

#define NEGF (-1e30f)
#define LOG2E 1.4426950408889634f
#define LN2 0.6931471805599453f

typedef __attribute__((ext_vector_type(8))) short short8;
typedef __attribute__((ext_vector_type(4))) float f32x4;

// round-to-nearest-even fp32 -> bf16 bits
__device__ __forceinline__ unsigned short f2bf(float f) {
  unsigned int u = __float_as_uint(f);
  u += 0x7fffu + ((u >> 16) & 1u);
  return (unsigned short)(u >> 16);
}

__device__ __forceinline__ void gload_lds16(const void* g, void* l) {
  __builtin_amdgcn_global_load_lds(
      (const __attribute__((address_space(1))) void*)g,
      (__attribute__((address_space(3))) void*)l, 16, 0, 0);
}

__device__ __forceinline__ float fexp2(float x) { return __builtin_amdgcn_exp2f(x); }
__device__ __forceinline__ float flog2(float x) { return __builtin_amdgcn_logf(x); }

// log-sum-exp of 3 in log2 domain (native v_exp/v_log, no ln2 muls)
__device__ __forceinline__ float lse3_2(float a, float b, float c) {
  float m = fmaxf(fmaxf(a, b), c);
  return m + flog2(fexp2(a - m) + fexp2(b - m) + fexp2(c - m));
}

// ---------------- convert kernels ----------------
__global__ void k_cvt(const float* __restrict__ src, unsigned short* __restrict__ dst, long n) {
  long i = ((long)blockIdx.x * blockDim.x + threadIdx.x) * 4;
  long stride = (long)gridDim.x * blockDim.x * 4;
  for (; i < n; i += stride) {
    float4 v = *(const float4*)(src + i);
    ushort4 o;
    o.x = f2bf(v.x); o.y = f2bf(v.y); o.z = f2bf(v.z); o.w = f2bf(v.w);
    *(ushort4*)(dst + i) = o;
  }
}

// W2 [101][512] fp32 -> padded [128][512] bf16 (rows >=101 zero)
__global__ void k_cvt_w2(const float* __restrict__ w2, unsigned short* __restrict__ dst) {
  int i = (blockIdx.x * blockDim.x + threadIdx.x) * 4;
  if (i >= 128 * 512) return;
  int c = i >> 9;
  float4 v = make_float4(0.f, 0.f, 0.f, 0.f);
  if (c < 101) v = *(const float4*)(w2 + i);
  ushort4 o;
  o.x = f2bf(v.x); o.y = f2bf(v.y); o.z = f2bf(v.z); o.w = f2bf(v.w);
  *(ushort4*)(dst + i) = o;
}

// ---------------- GEMM1: h = relu(X @ W1^T + b1), bf16 out ----------------
// X[64000][1024] bf16, W1[512][1024] bf16, H[64000][512] bf16
__global__ __launch_bounds__(256) void k_gemm1(
    const unsigned short* __restrict__ A,
    const unsigned short* __restrict__ B,
    const float* __restrict__ b1,
    unsigned short* __restrict__ H) {
  __shared__ __align__(16) char lds[32768];  // A tile [128][64] | B tile [128][64]
  const int K = 1024;
  int bid = blockIdx.x;
  // XCD-chunked swizzle, nwg=2000 (divisible by 8)
  int lid = (bid & 7) * 250 + (bid >> 3);
  int mt = lid >> 2, nt = lid & 3;
  int row0 = mt * 128, col0 = nt * 128;
  int tid = threadIdx.x;
  int lane = tid & 63, wid = tid >> 6;
  int wr = (wid >> 1) * 64, wc = (wid & 1) * 64;

  f32x4 acc[4][4];
#pragma unroll
  for (int i = 0; i < 4; ++i)
#pragma unroll
    for (int j = 0; j < 4; ++j) acc[i][j] = (f32x4){0.f, 0.f, 0.f, 0.f};

  for (int kt = 0; kt < 16; ++kt) {
    int k0 = kt * 64;
    __syncthreads();
#pragma unroll
    for (int r = 0; r < 4; ++r) {
      int c = r * 256 + tid;
      int trow = c >> 3;
      int sch = (c & 7) ^ (trow & 7);  // pre-swizzled global source chunk
      gload_lds16(A + (size_t)(row0 + trow) * K + (k0 + sch * 8), lds + c * 16);
      gload_lds16(B + (size_t)(col0 + trow) * K + (k0 + sch * 8), lds + 16384 + c * 16);
    }
    asm volatile("s_waitcnt vmcnt(0)" ::: "memory");
    __syncthreads();
#pragma unroll
    for (int kk = 0; kk < 2; ++kk) {
      int kb2 = (kk * 32 + ((lane >> 4) << 3)) * 2;  // byte offset along K
      short8 af[4], bfr[4];
#pragma unroll
      for (int i = 0; i < 4; ++i) {
        int ar = wr + i * 16 + (lane & 15);
        af[i] = *(const short8*)(lds + ((ar * 128 + kb2) ^ ((ar & 7) << 4)));
        int br = wc + i * 16 + (lane & 15);
        bfr[i] = *(const short8*)(lds + 16384 + ((br * 128 + kb2) ^ ((br & 7) << 4)));
      }
#pragma unroll
      for (int i = 0; i < 4; ++i)
#pragma unroll
        for (int j = 0; j < 4; ++j)
          acc[i][j] = __builtin_amdgcn_mfma_f32_16x16x32_bf16(af[i], bfr[j], acc[i][j], 0, 0, 0);
    }
  }
  int cl = lane & 15, r4 = (lane >> 4) << 2;
#pragma unroll
  for (int i = 0; i < 4; ++i) {
    int row = row0 + wr + i * 16 + r4;
#pragma unroll
    for (int j = 0; j < 4; ++j) {
      int col = col0 + wc + j * 16 + cl;
      float bb = b1[col];
#pragma unroll
      for (int q = 0; q < 4; ++q) {
        float v = acc[i][j][q] + bb;
        v = v > 0.f ? v : 0.f;
        H[(size_t)(row + q) * 512 + col] = f2bf(v);
      }
    }
  }
}

// ---------------- GEMM2 + log_softmax (writes log2-domain log-probs) ----------------
// Hm[64000][512] bf16, W2[128][512] bf16 (padded), LP[64000][101] fp32 (x log2e)
__global__ __launch_bounds__(256) void k_gemm2(
    const unsigned short* __restrict__ Hm,
    const unsigned short* __restrict__ W2,
    const float* __restrict__ b2,
    float* __restrict__ LP) {
  __shared__ __align__(16) char lds[32768];
  const int K = 512;
  int row0 = blockIdx.x * 128;
  int tid = threadIdx.x, lane = tid & 63, wid = tid >> 6;
  f32x4 acc[2][8];
#pragma unroll
  for (int i = 0; i < 2; ++i)
#pragma unroll
    for (int j = 0; j < 8; ++j) acc[i][j] = (f32x4){0.f, 0.f, 0.f, 0.f};

  for (int kt = 0; kt < 8; ++kt) {
    int k0 = kt * 64;
    __syncthreads();
#pragma unroll
    for (int r = 0; r < 4; ++r) {
      int c = r * 256 + tid;
      int trow = c >> 3;
      int sch = (c & 7) ^ (trow & 7);
      gload_lds16(Hm + (size_t)(row0 + trow) * K + (k0 + sch * 8), lds + c * 16);
      gload_lds16(W2 + (size_t)trow * K + (k0 + sch * 8), lds + 16384 + c * 16);
    }
    asm volatile("s_waitcnt vmcnt(0)" ::: "memory");
    __syncthreads();
#pragma unroll
    for (int kk = 0; kk < 2; ++kk) {
      int kb2 = (kk * 32 + ((lane >> 4) << 3)) * 2;
      short8 af[2], bfr[8];
#pragma unroll
      for (int i = 0; i < 2; ++i) {
        int ar = wid * 32 + i * 16 + (lane & 15);
        af[i] = *(const short8*)(lds + ((ar * 128 + kb2) ^ ((ar & 7) << 4)));
      }
#pragma unroll
      for (int j = 0; j < 8; ++j) {
        int br = j * 16 + (lane & 15);
        bfr[j] = *(const short8*)(lds + 16384 + ((br * 128 + kb2) ^ ((br & 7) << 4)));
      }
#pragma unroll
      for (int i = 0; i < 2; ++i)
#pragma unroll
        for (int j = 0; j < 8; ++j)
          acc[i][j] = __builtin_amdgcn_mfma_f32_16x16x32_bf16(af[i], bfr[j], acc[i][j], 0, 0, 0);
    }
  }
  // epilogue: bias + row log_softmax over cols 0..100, write fp32 * log2e
  int cl = lane & 15, r4 = (lane >> 4) << 2;
#pragma unroll
  for (int i = 0; i < 2; ++i) {
#pragma unroll
    for (int q = 0; q < 4; ++q) {
      int row = row0 + wid * 32 + i * 16 + r4 + q;
      float v[8];
      float mx = NEGF;
#pragma unroll
      for (int j = 0; j < 8; ++j) {
        int col = j * 16 + cl;
        float t = acc[i][j][q];
        if (col < 101) {
          t += b2[col];
          mx = fmaxf(mx, t);
        }
        v[j] = t;
      }
#pragma unroll
      for (int m = 1; m < 16; m <<= 1) mx = fmaxf(mx, __shfl_xor(mx, m));
      float s = 0.f;
#pragma unroll
      for (int j = 0; j < 8; ++j) {
        int col = j * 16 + cl;
        if (col < 101) s += __expf(v[j] - mx);
      }
#pragma unroll
      for (int m = 1; m < 16; m <<= 1) s += __shfl_xor(s, m);
      float lse = mx + __logf(s);
#pragma unroll
      for (int j = 0; j < 8; ++j) {
        int col = j * 16 + cl;
        if (col < 101) LP[(size_t)row * 101 + col] = (v[j] - lse) * LOG2E;
      }
    }
  }
}

// ---------------- CTC alpha recursion: one wave per batch element ----------------
// Works entirely in log2 domain. 8-deep row prefetch pipeline.
__global__ __launch_bounds__(64) void k_ctc(
    const float* __restrict__ LP,
    const int* __restrict__ tgt_all,
    const int* __restrict__ dlen,
    const int* __restrict__ tlen,
    float* __restrict__ lossout) {
  int b = blockIdx.x;
  int lane = threadIdx.x;
  const float* lp = LP + (size_t)b * 1000 * 101;
  int Tb = dlen[b];
  int Ub = tlen[b];
  const int* tg = tgt_all + b * 200;

  // state s = lane*7 + j; invalid states (s>=401) compute garbage-but-finite
  // values that can never flow into valid states (transitions only go upward).
  int cls[7], sk[7];
#pragma unroll
  for (int j = 0; j < 7; ++j) {
    int s = lane * 7 + j;
    int c = 100, skp = 0;
    if (s < 401 && (s & 1)) {
      int u = (s - 1) >> 1;
      c = tg[u];
      if (s >= 3) skp = (tg[u] != tg[u - 1]) ? 1 : 0;
    }
    cls[j] = c; sk[j] = skp;
  }

  float al[7];
#pragma unroll
  for (int j = 0; j < 7; ++j) {
    int s = lane * 7 + j;
    al[j] = (s <= 1) ? lp[cls[j]] : NEGF;  // t=0 init (log2 domain)
  }

  float pf[8][7];
#define LOADROW(tt, bi)                                      \
  do {                                                       \
    int ttc = (tt) < 1000 ? (tt) : 999;                      \
    const float* rp = lp + (size_t)ttc * 101;                \
    pf[bi][0] = rp[cls[0]]; pf[bi][1] = rp[cls[1]];          \
    pf[bi][2] = rp[cls[2]]; pf[bi][3] = rp[cls[3]];          \
    pf[bi][4] = rp[cls[4]]; pf[bi][5] = rp[cls[5]];          \
    pf[bi][6] = rp[cls[6]];                                  \
  } while (0)

  LOADROW(1, 0); LOADROW(2, 1); LOADROW(3, 2); LOADROW(4, 3);
  LOADROW(5, 4); LOADROW(6, 5); LOADROW(7, 6); LOADROW(8, 7);

#define STEP(tt, cb)                                                         \
  do {                                                                       \
    if ((tt) < Tb) {                                                         \
      float u6 = __shfl_up(al[6], 1);                                        \
      float u5 = __shfl_up(al[5], 1);                                        \
      if (lane == 0) { u6 = NEGF; u5 = NEGF; }                               \
      float na0 = lse3_2(al[0], u6, sk[0] ? u5 : NEGF) + pf[cb][0];          \
      float na1 = lse3_2(al[1], al[0], sk[1] ? u6 : NEGF) + pf[cb][1];       \
      float na2 = lse3_2(al[2], al[1], sk[2] ? al[0] : NEGF) + pf[cb][2];    \
      float na3 = lse3_2(al[3], al[2], sk[3] ? al[1] : NEGF) + pf[cb][3];    \
      float na4 = lse3_2(al[4], al[3], sk[4] ? al[2] : NEGF) + pf[cb][4];    \
      float na5 = lse3_2(al[5], al[4], sk[5] ? al[3] : NEGF) + pf[cb][5];    \
      float na6 = lse3_2(al[6], al[5], sk[6] ? al[4] : NEGF) + pf[cb][6];    \
      al[0] = na0; al[1] = na1; al[2] = na2; al[3] = na3;                    \
      al[4] = na4; al[5] = na5; al[6] = na6;                                 \
      LOADROW((tt) + 8, cb);                                                 \
    }                                                                        \
  } while (0)

  for (int t = 1; t < Tb; t += 8) {
    STEP(t, 0); STEP(t + 1, 1); STEP(t + 2, 2); STEP(t + 3, 3);
    STEP(t + 4, 4); STEP(t + 5, 5); STEP(t + 6, 6); STEP(t + 7, 7);
  }

  __shared__ float sal[401];
#pragma unroll
  for (int j = 0; j < 7; ++j) {
    int s = lane * 7 + j;
    if (s < 401) sal[s] = al[j];
  }
  __syncthreads();
  if (lane == 0) {
    float l1 = sal[2 * Ub];
    float l2 = sal[2 * Ub - 1];
    float m = fmaxf(l1, l2);
    float l2sum = m + flog2(fexp2(l1 - m) + fexp2(l2 - m));  // log2 domain
    lossout[b] = (-LN2 * l2sum) / (float)Tb;                  // back to nat log
  }
#undef STEP
#undef LOADROW
}

__global__ void k_reduce(const float* __restrict__ lossv, float* __restrict__ out) {
  float v = lossv[threadIdx.x];
#pragma unroll
  for (int m = 1; m < 64; m <<= 1) v += __shfl_xor(v, m);
  if (threadIdx.x == 0) out[0] = v * (1.0f / 64.0f);
}

extern "C" void kernel_launch(void* const* d_in, const int* in_sizes, int n_in,
                              void* d_out, int out_size, void* d_ws, size_t ws_size,
                              hipStream_t stream) {
  const float* X  = (const float*)d_in[0];
  const int* tgt  = (const int*)d_in[1];
  const int* dlen = (const int*)d_in[2];
  const int* tlen = (const int*)d_in[3];
  const float* W1 = (const float*)d_in[4];
  const float* b1 = (const float*)d_in[5];
  const float* W2 = (const float*)d_in[6];
  const float* b2 = (const float*)d_in[7];

  char* ws = (char*)d_ws;
  unsigned short* Xbf  = (unsigned short*)(ws);              // 131,072,000 B
  float* LP            = (float*)(ws);                       // overlaps Xbf (Xbf dead after gemm1)
  unsigned short* W1bf = (unsigned short*)(ws + 131072000);  // 1,048,576 B
  unsigned short* W2bf = (unsigned short*)(ws + 132120576);  // 131,072 B
  unsigned short* Hbf  = (unsigned short*)(ws + 132251648);  // 65,536,000 B
  float* lossv         = (float*)(ws + 197787648);           // 256 B

  k_cvt<<<4096, 256, 0, stream>>>(X, Xbf, 65536000L);
  k_cvt<<<512, 256, 0, stream>>>(W1, W1bf, 524288L);
  k_cvt_w2<<<64, 256, 0, stream>>>(W2, W2bf);
  k_gemm1<<<2000, 256, 0, stream>>>(Xbf, W1bf, b1, Hbf);
  k_gemm2<<<500, 256, 0, stream>>>(Hbf, W2bf, b2, LP);
  k_ctc<<<64, 64, 0, stream>>>(LP, tgt, dlen, tlen, lossv);
  k_reduce<<<1, 64, 0, stream>>>(lossv, (float*)d_out);
}